// Round 1
// 834.703 us; speedup vs baseline: 1.3055x; 1.3055x over previous
//
#include <hip/hip_runtime.h>
#include <hip/hip_bf16.h>

// CAGAT_MinSum_Layer_Lite — gather-free radix partition + compute-in-reduce.
//
// Evidence trail:
//  R1/R3: global fp32 atomicAdd executes at the memory fabric regardless of
//         scope -> ~20.6 G atomics/s hard ceiling. Global-atomic formulations dead.
//  R2:    per-record 8 B scatter cost partial-line RMW -> LDS counting-sort with
//         coalesced copy-out.
//  R4(now): p2 at 27% HBM / 6% VALU / 39% occ was TCP-bound on 2x33.5M random
//         4 B nf gathers (each wave64 gather = up to 64 L1-line transactions).
//         Fix: defer the message math to P3 where the sort makes x_dst a
//         16 KB LDS-window lookup; P2 carries raw (src,dstlow,cm) in 8 B
//         records (256 buckets so src:20b|dstlow:12b fits 32 bits).
//
// P1   : per-block bucket histogram, per-wave sub-hists (bucket = dst>>12)
// scan1: per-bucket exclusive prefix over blocks (in place)
// scan2: exclusive prefix of bucket totals
// P2   : per 4096-edge tile: LDS hist -> scan -> rank -> permute -> coalesced
//        copy-out of (src<<12|dstlow, cm) records to exact slots. NO gathers.
// P3   : bucket x 4 slices; preload 16 KB nf window to LDS; coalesced record
//        read -> ONE random nf[src] gather -> edge_msg -> 16 KB LDS fp32
//        accumulate -> partial store (everything overwritten; poison-safe)
// P4   : sum 4 partials -> out

#define THREADS 256
#define NBLK    1024            // P1/P2 partition blocks
#define NBUCK   256             // buckets
#define BSH     12              // bucket = dst >> 12  (4096 nodes/bucket)
#define NPB     (1 << BSH)      // nodes per bucket
#define TILE    4096            // edges per P2 tile
#define NSLICE  4               // P3 slices per bucket
#define NPAD    (NBUCK << BSH)  // padded node space = 1048576 (== 1<<20)

__device__ __forceinline__ float edge_msg(float xs, float xd, float cc,
                                          float W0, float W1, float W2,
                                          float bb, float ms, float cp) {
    float raw = fmaf(xs, W0, fmaf(xd, W1, fmaf(cc, W2, bb)));
    raw = (raw > 0.0f) ? raw : 0.01f * raw;            // leaky_relu
    raw = fmaf(cc, cp, raw);
    const float att = __builtin_amdgcn_rcpf(1.0f + __expf(-raw));  // sigmoid
    return xs * att * ms;
}

__global__ __launch_bounds__(THREADS) void p1_hist(
    const int* __restrict__ dsts, int E, int epb,
    unsigned int* __restrict__ histT)
{
    __shared__ unsigned int h[4][NBUCK];          // per-wave sub-hists, 4 KB
    const int t = threadIdx.x;                    // THREADS == NBUCK
#pragma unroll
    for (int w = 0; w < 4; ++w) h[w][t] = 0u;
    __syncthreads();

    const int wid   = t >> 6;
    const int blk   = blockIdx.x;
    const int start = blk * epb;
    const int end   = min(E, start + epb);
    const int n     = end - start;
    const int nvec  = n >> 2;

    for (int i = t; i < nvec; i += THREADS) {
        const int4 d4 = *(const int4*)(dsts + start + (i << 2));
        atomicAdd(&h[wid][d4.x >> BSH], 1u);
        atomicAdd(&h[wid][d4.y >> BSH], 1u);
        atomicAdd(&h[wid][d4.z >> BSH], 1u);
        atomicAdd(&h[wid][d4.w >> BSH], 1u);
    }
    for (int e = start + (nvec << 2) + t; e < end; e += THREADS)
        atomicAdd(&h[wid][dsts[e] >> BSH], 1u);

    __syncthreads();
    histT[(size_t)t * NBLK + blk] = h[0][t] + h[1][t] + h[2][t] + h[3][t];
}

// one block per bucket: exclusive prefix over its NBLK counts, in place
__global__ __launch_bounds__(THREADS) void p_scan1(
    unsigned int* __restrict__ histT, unsigned int* __restrict__ totals)
{
    const int b = blockIdx.x;
    unsigned int* row = histT + (size_t)b * NBLK;
    const int t = threadIdx.x;

    uint4 c = *(uint4*)(row + (t << 2));      // NBLK = 256*4
    const unsigned s1 = c.x;
    const unsigned s2 = c.x + c.y;
    const unsigned s3 = s2 + c.z;
    const unsigned tsum = s3 + c.w;

    __shared__ unsigned int ls[THREADS];
    ls[t] = tsum;
    __syncthreads();
    for (int off = 1; off < THREADS; off <<= 1) {
        unsigned tmp = 0u;
        if (t >= off) tmp = ls[t - off];
        __syncthreads();
        if (t >= off) ls[t] += tmp;
        __syncthreads();
    }
    const unsigned base = (t == 0) ? 0u : ls[t - 1];

    uint4 o;
    o.x = base; o.y = base + s1; o.z = base + s2; o.w = base + s3;
    *(uint4*)(row + (t << 2)) = o;
    if (t == 0) totals[b] = ls[THREADS - 1];
}

__global__ __launch_bounds__(NBUCK) void p_scan2(
    const unsigned int* __restrict__ totals, unsigned int* __restrict__ bucketBase)
{
    __shared__ unsigned int ls[NBUCK];
    const int t = threadIdx.x;
    ls[t] = totals[t];
    __syncthreads();
    for (int off = 1; off < NBUCK; off <<= 1) {
        unsigned tmp = 0u;
        if (t >= off) tmp = ls[t - off];
        __syncthreads();
        if (t >= off) ls[t] += tmp;
        __syncthreads();
    }
    bucketBase[t] = (t == 0) ? 0u : ls[t - 1];
}

__global__ __launch_bounds__(THREADS) void p2_partition(
    const int*   __restrict__ srcs,
    const int*   __restrict__ dsts,
    const float* __restrict__ cm,
    const unsigned int* __restrict__ relT,        // scanned histT
    const unsigned int* __restrict__ bucketBase,
    uint2* __restrict__ recs, int E, int epb)
{
    __shared__ unsigned int cur[NBUCK];      // block's running global cursor / bucket
    __shared__ unsigned int hist[NBUCK];
    __shared__ unsigned int scanT[NBUCK];
    __shared__ unsigned int rankCur[NBUCK];  // mutable rank cursors (pass 2)
    __shared__ unsigned int delta[NBUCK];    // cur - excl (global slot = rank + delta)
    __shared__ uint2        buf[TILE];       // 32 KB bucket-sorted record buffer
    __shared__ unsigned int slotArr[TILE];   // 16 KB precomputed global slots

    const int blk = blockIdx.x;
    const int t   = threadIdx.x;             // THREADS == NBUCK
    cur[t] = bucketBase[t] + relT[(size_t)t * NBLK + blk];

    const int start = blk * epb;
    const int end   = min(E, start + epb);

    for (int t0 = start; t0 < end; t0 += TILE) {
        const int n    = min(end - t0, TILE);
        const int nvec = n >> 2;

        // --- pass 1: tile histogram of dst ---
        hist[t] = 0u;
        __syncthreads();
        for (int i = t; i < nvec; i += THREADS) {
            const int4 d4 = *(const int4*)(dsts + t0 + (i << 2));
            atomicAdd(&hist[d4.x >> BSH], 1u);
            atomicAdd(&hist[d4.y >> BSH], 1u);
            atomicAdd(&hist[d4.z >> BSH], 1u);
            atomicAdd(&hist[d4.w >> BSH], 1u);
        }
        for (int e = t0 + (nvec << 2) + t; e < t0 + n; e += THREADS)
            atomicAdd(&hist[dsts[e] >> BSH], 1u);
        __syncthreads();

        // --- inclusive scan over 256 buckets (all threads participate) ---
        scanT[t] = hist[t];
        __syncthreads();
        for (int off = 1; off < NBUCK; off <<= 1) {
            unsigned v = 0u;
            if (t >= off) v = scanT[t - off];
            __syncthreads();
            if (t >= off) scanT[t] += v;
            __syncthreads();
        }
        {
            const unsigned excl = scanT[t] - hist[t];   // exclusive
            rankCur[t] = excl;
            delta[t]   = cur[t] - excl;                 // may "wrap"; slot math mod 2^32
        }
        __syncthreads();

        // --- pass 2: rank + permute into LDS. NO global gathers, no msg math ---
        for (int i = t; i < nvec; i += THREADS) {
            const int base = t0 + (i << 2);
            const int4   s4 = *(const int4*)  (srcs + base);
            const int4   d4 = *(const int4*)  (dsts + base);
            const float4 c4 = *(const float4*)(cm   + base);
            const unsigned s[4] = {(unsigned)s4.x, (unsigned)s4.y, (unsigned)s4.z, (unsigned)s4.w};
            const unsigned d[4] = {(unsigned)d4.x, (unsigned)d4.y, (unsigned)d4.z, (unsigned)d4.w};
            const float    c[4] = {c4.x, c4.y, c4.z, c4.w};
#pragma unroll
            for (int k = 0; k < 4; ++k) {
                const unsigned b = d[k] >> BSH;
                const unsigned r = atomicAdd(&rankCur[b], 1u);
                buf[r] = make_uint2((s[k] << BSH) | (d[k] & (NPB - 1u)),
                                    __float_as_uint(c[k]));
                slotArr[r] = r + delta[b];
            }
        }
        for (int e = t0 + (nvec << 2) + t; e < t0 + n; e += THREADS) {
            const unsigned dv = (unsigned)dsts[e];
            const unsigned b  = dv >> BSH;
            const unsigned r  = atomicAdd(&rankCur[b], 1u);
            buf[r] = make_uint2(((unsigned)srcs[e] << BSH) | (dv & (NPB - 1u)),
                                __float_as_uint(cm[e]));
            slotArr[r] = r + delta[b];
        }
        __syncthreads();

        // --- coalesced copy-out: consecutive j in a bucket -> consecutive slot ---
        for (int j = t; j < n; j += THREADS)
            recs[slotArr[j]] = buf[j];
        __syncthreads();
        cur[t] += hist[t];
        __syncthreads();
    }
}

__global__ __launch_bounds__(THREADS) void p3_reduce(
    const uint2* __restrict__ recs,
    const unsigned int* __restrict__ totals,
    const unsigned int* __restrict__ bucketBase,
    const float* __restrict__ nf, int N,
    const float* __restrict__ Wp, const float* __restrict__ bp,
    const float* __restrict__ msp, const float* __restrict__ cpp_,
    float* __restrict__ partials)            // [NSLICE][NPAD]
{
    __shared__ float acc[NPB];               // 16 KB accumulator
    __shared__ float nfw[NPB];               // 16 KB nf window (x_dst is bucket-local)
    const int b = blockIdx.x / NSLICE;
    const int s = blockIdx.x % NSLICE;
    const int t = threadIdx.x;
    const int nbase = b << BSH;

    for (int j = t; j < NPB; j += THREADS) {
        acc[j] = 0.0f;
        const int g = nbase + j;
        nfw[j] = (g < N) ? nf[g] : 0.0f;
    }
    __syncthreads();

    const float W0 = Wp[0], W1 = Wp[1], W2 = Wp[2];
    const float bb = bp[0], ms = msp[0], cp = cpp_[0];

    const unsigned cnt   = totals[b];
    const unsigned base  = bucketBase[b];
    const unsigned chunk = (cnt + NSLICE - 1) / NSLICE;
    unsigned k0 = min(cnt, s * chunk);
    unsigned k1 = min(cnt, k0 + chunk);
    unsigned g0 = base + k0, g1 = base + k1;

    // scalar head/tail so the main loop runs 16 B-aligned uint4 (2 records)
    if ((g0 & 1u) && g0 < g1) {
        if (t == 0) {
            const uint2 r = recs[g0];
            const unsigned dl = r.x & (NPB - 1u);
            atomicAdd(&acc[dl], edge_msg(nf[r.x >> BSH], nfw[dl],
                                         __uint_as_float(r.y),
                                         W0, W1, W2, bb, ms, cp));
        }
        ++g0;
    }
    if (g0 < g1 && ((g1 - g0) & 1u)) {
        --g1;
        if (t == 0) {
            const uint2 r = recs[g1];
            const unsigned dl = r.x & (NPB - 1u);
            atomicAdd(&acc[dl], edge_msg(nf[r.x >> BSH], nfw[dl],
                                         __uint_as_float(r.y),
                                         W0, W1, W2, bb, ms, cp));
        }
    }
    const unsigned np = (g1 > g0) ? ((g1 - g0) >> 1) : 0u;
    for (unsigned p = t; p < np; p += THREADS) {
        const uint4 q = *(const uint4*)(recs + g0 + (p << 1));
        // issue both random gathers before the dependent math (ILP)
        const float xs0 = nf[q.x >> BSH];
        const float xs1 = nf[q.z >> BSH];
        const unsigned dl0 = q.x & (NPB - 1u);
        const unsigned dl1 = q.z & (NPB - 1u);
        const float m0 = edge_msg(xs0, nfw[dl0], __uint_as_float(q.y),
                                  W0, W1, W2, bb, ms, cp);
        const float m1 = edge_msg(xs1, nfw[dl1], __uint_as_float(q.w),
                                  W0, W1, W2, bb, ms, cp);
        atomicAdd(&acc[dl0], m0);
        atomicAdd(&acc[dl1], m1);
    }
    __syncthreads();

    // partial store (always, even for empty slices: ws is poisoned)
    float* dst = partials + (size_t)s * NPAD + ((size_t)b << BSH);
    for (int j = t << 2; j < NPB; j += THREADS << 2)
        *(float4*)(dst + j) = *(float4*)(acc + j);
}

__global__ __launch_bounds__(THREADS) void p4_sum(
    const float* __restrict__ partials, float* __restrict__ out, int N)
{
    const int b4 = (blockIdx.x * blockDim.x + threadIdx.x) << 2;
    if (b4 + 3 < N) {
        float4 a = *(const float4*)(partials + b4);
#pragma unroll
        for (int s = 1; s < NSLICE; ++s) {
            const float4 v = *(const float4*)(partials + (size_t)s * NPAD + b4);
            a.x += v.x; a.y += v.y; a.z += v.z; a.w += v.w;
        }
        *(float4*)(out + b4) = a;
    } else if (b4 < N) {
        for (int j = b4; j < N; ++j) {
            float a = 0.0f;
#pragma unroll
            for (int s = 0; s < NSLICE; ++s) a += partials[(size_t)s * NPAD + j];
            out[j] = a;
        }
    }
}

// ---- proven fallback (round-1 kernel) if ws is too small ----
__global__ __launch_bounds__(THREADS) void cagat_atomic_fallback(
    const float* __restrict__ nf, const int* __restrict__ srcs,
    const int* __restrict__ dsts, const float* __restrict__ cm,
    const float* __restrict__ Wp, const float* __restrict__ bp,
    const float* __restrict__ msp, const float* __restrict__ cpp_,
    float* __restrict__ out, int E)
{
    const float W0 = Wp[0], W1 = Wp[1], W2 = Wp[2];
    const float bb = bp[0], ms = msp[0], cp = cpp_[0];
    const int i = blockIdx.x * blockDim.x + threadIdx.x;
    for (int e = i; e < E; e += gridDim.x * blockDim.x) {
        const float msg = edge_msg(nf[srcs[e]], nf[dsts[e]], cm[e],
                                   W0, W1, W2, bb, ms, cp);
        atomicAdd(out + dsts[e], msg);
    }
}

extern "C" void kernel_launch(void* const* d_in, const int* in_sizes, int n_in,
                              void* d_out, int out_size, void* d_ws, size_t ws_size,
                              hipStream_t stream) {
    const float* nf   = (const float*)d_in[0];
    const int*   eidx = (const int*)  d_in[1];   // [2, E]: src row then dst row
    const float* cm   = (const float*)d_in[2];
    const float* W    = (const float*)d_in[3];
    const float* b    = (const float*)d_in[4];
    const float* ms   = (const float*)d_in[5];
    const float* cp   = (const float*)d_in[6];
    float*       out  = (float*)d_out;

    const int E = in_sizes[2];
    const int N = in_sizes[0];
    const int* srcs = eidx;
    const int* dsts = eidx + E;

    const size_t recs_bytes = (size_t)E * 8u;
    const size_t hist_bytes = (size_t)NBUCK * NBLK * 4u;         // 1 MB
    const size_t tot_bytes  = 2u * (size_t)NBUCK * 4u;           // totals + base
    const size_t part_bytes = (size_t)NSLICE * NPAD * 4u;        // 16 MB
    const size_t need = recs_bytes + hist_bytes + tot_bytes + part_bytes;

    if (ws_size < need || N > NPAD) {                // NPAD == 1<<20: pack-width guard
        hipMemsetAsync(d_out, 0, (size_t)out_size * sizeof(float), stream);
        cagat_atomic_fallback<<<8192, THREADS, 0, stream>>>(
            nf, srcs, dsts, cm, W, b, ms, cp, out, E);
        return;
    }

    char* wsb = (char*)d_ws;
    uint2*        recs       = (uint2*)wsb;
    unsigned int* histT      = (unsigned int*)(wsb + recs_bytes);
    unsigned int* totals     = (unsigned int*)(wsb + recs_bytes + hist_bytes);
    unsigned int* bucketBase = totals + NBUCK;
    float*        partials   = (float*)(wsb + recs_bytes + hist_bytes + tot_bytes);

    const int epb = (E + NBLK - 1) / NBLK;       // 32768 for E=2^25

    p1_hist<<<NBLK, THREADS, 0, stream>>>(dsts, E, epb, histT);
    p_scan1<<<NBUCK, THREADS, 0, stream>>>(histT, totals);
    p_scan2<<<1, NBUCK, 0, stream>>>(totals, bucketBase);
    p2_partition<<<NBLK, THREADS, 0, stream>>>(
        srcs, dsts, cm, histT, bucketBase, recs, E, epb);
    p3_reduce<<<NBUCK * NSLICE, THREADS, 0, stream>>>(
        recs, totals, bucketBase, nf, N, W, b, ms, cp, partials);
    p4_sum<<<(N + 4 * THREADS - 1) / (4 * THREADS), THREADS, 0, stream>>>(
        partials, out, N);
}